// Round 6
// baseline (1191.167 us; speedup 1.0000x reference)
//
#include <hip/hip_runtime.h>

// CRF Viterbi decode: B=256, T=512, K=256, out (B, 514) as int32 tags.
// fwd: one block/batch, 16 waves. Wave g owns i-rows [16g,16g+16); lane
// owns j-cols [4*lane, 4*lane+4) as 16 named v4f trans registers.
// Per step: 4 uniform ds_read_b128 state broadcasts, 16 v4f adds,
// 4 fmax + 28 asm v_max3_f32, part write; barrier; distributed fold:
// each wave reduces the 16 partials for its OWN state slice via one
// ds_read_b128 + 4-level shfl_xor butterfly, + prefetched em, mask,
// writes double-buffered st + global states row; barrier.
// bwd: recompute backpointers via exact f32 equality scan (unchanged).
// ws layout: states[B*T*K] f32 (128 MiB) + transT[K*K] f32 (256 KiB).

#define TK 256
#define TT 512

typedef float v4f __attribute__((ext_vector_type(4)));

__device__ __forceinline__ float max3f(float a, float b, float c) {
  float d;
  asm("v_max3_f32 %0, %1, %2, %3" : "=v"(d) : "v"(a), "v"(b), "v"(c));
  return d;
}

__global__ void transpose_kernel(const float* __restrict__ trans,
                                 float* __restrict__ transT) {
  int j = blockIdx.x;
  int i = threadIdx.x;
  transT[(size_t)j * TK + i] = trans[(size_t)i * TK + j];
}

__global__ __launch_bounds__(1024)
__attribute__((amdgpu_waves_per_eu(4, 4)))
void crf_fwd(const float* __restrict__ em,
             const float* __restrict__ trans,
             const int* __restrict__ mask,
             float* __restrict__ states) {
  const int b = blockIdx.x;
  const int tid = threadIdx.x;
  const int lane = tid & 63;
  const int g = tid >> 6;        // wave 0..15: i-rows [16g, 16g+16)
  const int c = lane & 3;
  const int j0 = 4 * lane;       // compute-phase columns
  const int fj = 16 * g + 4 * c; // fold-phase columns (this wave's state slice)

  __shared__ __align__(16) float st[2][TK];     // double-buffered state
  __shared__ __align__(16) v4f part[16][64];    // per-wave partial maxes
  __shared__ int mk[TT];

  // trans payload: 16 named v4f = rows 16g..16g+15, cols j0..j0+3
  const float* tb = trans + (size_t)(16 * g) * TK + j0;
#define TRD(n) const v4f t##n = *reinterpret_cast<const v4f*>(tb + (n) * TK);
  TRD(0) TRD(1) TRD(2) TRD(3) TRD(4) TRD(5) TRD(6) TRD(7)
  TRD(8) TRD(9) TRD(10) TRD(11) TRD(12) TRD(13) TRD(14) TRD(15)
#undef TRD

  if (tid < TT) mk[tid] = mask[(size_t)b * TT + tid];

  const size_t base = (size_t)b * TT * TK;
  if (lane < 4) {
    const v4f s0 = *reinterpret_cast<const v4f*>(em + base + 16 * g + 4 * lane);
    *reinterpret_cast<v4f*>(&st[0][16 * g + 4 * lane]) = s0;
    *reinterpret_cast<v4f*>(states + base + 16 * g + 4 * lane) = s0;
  }
  __syncthreads();

  const float* emf = em + base + fj;              // + t*TK per step
  float* stg = states + base + 16 * g + 4 * lane; // lanes<4 store; + t*TK

  for (int t = 1; t < TT; ++t) {
    const int rd = (t - 1) & 1, wr = t & 1;
    // off-path prefetches for the fold phase
    const v4f emv = *reinterpret_cast<const v4f*>(emf + (size_t)t * TK);
    const int mkt = mk[t];
    const v4f OS = *reinterpret_cast<const v4f*>(&st[rd][fj]);

    // uniform state broadcasts (4x ds_read_b128)
    const float* sp = &st[rd][16 * g];
    const v4f S0 = *reinterpret_cast<const v4f*>(sp);
    const v4f S1 = *reinterpret_cast<const v4f*>(sp + 4);
    const v4f S2 = *reinterpret_cast<const v4f*>(sp + 8);
    const v4f S3 = *reinterpret_cast<const v4f*>(sp + 12);

    v4f acc;
    {
      const v4f a0 = t0 + S0.x;
      const v4f b0 = t1 + S0.y;
      acc.x = fmaxf(a0.x, b0.x);
      acc.y = fmaxf(a0.y, b0.y);
      acc.z = fmaxf(a0.z, b0.z);
      acc.w = fmaxf(a0.w, b0.w);
    }
#define ROWPAIR(tA, tB, sA, sB)            \
    {                                      \
      const v4f aa = tA + sA;              \
      const v4f bb = tB + sB;              \
      acc.x = max3f(acc.x, aa.x, bb.x);    \
      acc.y = max3f(acc.y, aa.y, bb.y);    \
      acc.z = max3f(acc.z, aa.z, bb.z);    \
      acc.w = max3f(acc.w, aa.w, bb.w);    \
    }
    ROWPAIR(t2, t3, S0.z, S0.w)
    ROWPAIR(t4, t5, S1.x, S1.y)
    ROWPAIR(t6, t7, S1.z, S1.w)
    ROWPAIR(t8, t9, S2.x, S2.y)
    ROWPAIR(t10, t11, S2.z, S2.w)
    ROWPAIR(t12, t13, S3.x, S3.y)
    ROWPAIR(t14, t15, S3.z, S3.w)
#undef ROWPAIR

    part[g][lane] = acc;
    __syncthreads();

    // distributed fold: max over the 16 partials for this wave's slice
    v4f P = part[lane >> 2][4 * g + c];
#pragma unroll
    for (int m = 4; m <= 32; m <<= 1) {
      P.x = fmaxf(P.x, __shfl_xor(P.x, m, 64));
      P.y = fmaxf(P.y, __shfl_xor(P.y, m, 64));
      P.z = fmaxf(P.z, __shfl_xor(P.z, m, 64));
      P.w = fmaxf(P.w, __shfl_xor(P.w, m, 64));
    }
    v4f nw;
    nw.x = (mkt > 0) ? P.x + emv.x : OS.x;
    nw.y = (mkt > 0) ? P.y + emv.y : OS.y;
    nw.z = (mkt > 0) ? P.z + emv.z : OS.z;
    nw.w = (mkt > 0) ? P.w + emv.w : OS.w;
    if (lane < 4) {
      *reinterpret_cast<v4f*>(&st[wr][16 * g + 4 * lane]) = nw;
      *reinterpret_cast<v4f*>(stg + (size_t)t * TK) = nw;
    }
    __syncthreads();
  }
}

__device__ __forceinline__ float wave_max(float m) {
#pragma unroll
  for (int d = 1; d < 64; d <<= 1) m = fmaxf(m, __shfl_xor(m, d, 64));
  return m;
}

// First index i (lane-major: i = 4*lane + k) whose value equals m.
__device__ __forceinline__ int first_eq_idx(float s0, float s1, float s2,
                                            float s3, float m) {
  unsigned long long b0 = __ballot(s0 == m);
  unsigned long long b1 = __ballot(s1 == m);
  unsigned long long b2 = __ballot(s2 == m);
  unsigned long long b3 = __ballot(s3 == m);
  int best = 0x7fffffff;
  if (b0) best = min(best, 4 * (__ffsll(b0) - 1) + 0);
  if (b1) best = min(best, 4 * (__ffsll(b1) - 1) + 1);
  if (b2) best = min(best, 4 * (__ffsll(b2) - 1) + 2);
  if (b3) best = min(best, 4 * (__ffsll(b3) - 1) + 3);
  return best;
}

// Backward: one wave per batch; 511 serial steps. Recomputes the forward
// argmax exactly (f32 add/max bit-exact; first-occurrence tie-break).
__global__ __launch_bounds__(64, 1) void crf_bwd(const float* __restrict__ states,
                                                 const float* __restrict__ transT,
                                                 const int* __restrict__ mask,
                                                 int* __restrict__ out,
                                                 int out_stride) {
  const int b = blockIdx.x;
  const int lane = threadIdx.x;

  __shared__ int mk[TT];
  for (int q = lane; q < TT; q += 64) mk[q] = mask[(size_t)b * TT + q];
  __syncthreads();

  const size_t sbase = (size_t)b * TT * TK;
  int* outp = out + (size_t)b * out_stride;

  // zero the pad region (harness poisons d_out once)
  for (int q = TT + lane; q < out_stride; q += 64) outp[q] = 0;

  const float* srow = states + sbase;
  float4 r = *reinterpret_cast<const float4*>(srow + (size_t)(TT - 1) * TK + 4 * lane);
  float lm = fmaxf(fmaxf(r.x, r.y), fmaxf(r.z, r.w));
  lm = wave_max(lm);
  int tag = first_eq_idx(r.x, r.y, r.z, r.w, lm);

  auto LOADROW = [&](int rr) -> float4 {
    return *reinterpret_cast<const float4*>(srow + (size_t)rr * TK + 4 * lane);
  };
  float4 p0 = LOADROW(TT - 2), p1 = LOADROW(TT - 3), p2 = LOADROW(TT - 4),
         p3 = LOADROW(TT - 5);

  auto STEP = [&](float4 pr, int t) {
    int mkt = mk[t];
    if (lane == 0) outp[t] = (mkt > 0) ? tag : 0;  // tags * mask
    const float4 tv =
        *reinterpret_cast<const float4*>(transT + (size_t)tag * TK + 4 * lane);
    float s0 = pr.x + tv.x;
    float s1 = pr.y + tv.y;
    float s2 = pr.z + tv.z;
    float s3 = pr.w + tv.w;
    float m = fmaxf(fmaxf(s0, s1), fmaxf(s2, s3));
    m = wave_max(m);
    int prev = first_eq_idx(s0, s1, s2, s3, m);
    tag = (mkt > 0) ? prev : tag;
  };

  int t = TT - 1;
  while (t >= 4) {
    STEP(p0, t);     if (t - 5 >= 0) p0 = LOADROW(t - 5);
    STEP(p1, t - 1); if (t - 6 >= 0) p1 = LOADROW(t - 6);
    STEP(p2, t - 2); if (t - 7 >= 0) p2 = LOADROW(t - 7);
    STEP(p3, t - 3); if (t - 8 >= 0) p3 = LOADROW(t - 8);
    t -= 4;
  }
  STEP(p0, 3);
  STEP(p1, 2);
  STEP(p2, 1);
  if (lane == 0) outp[0] = (mk[0] > 0) ? tag : 0;
}

extern "C" void kernel_launch(void* const* d_in, const int* in_sizes, int n_in,
                              void* d_out, int out_size, void* d_ws, size_t ws_size,
                              hipStream_t stream) {
  const float* em = (const float*)d_in[0];
  const float* trans = (const float*)d_in[1];
  const int* mask = (const int*)d_in[2];
  int* out = (int*)d_out;

  const int B = in_sizes[0] / (TT * TK);      // 256
  const int out_stride = out_size / B;        // 514

  float* states = (float*)d_ws;
  float* transT = states + (size_t)B * TT * TK;

  transpose_kernel<<<TK, TK, 0, stream>>>(trans, transT);
  crf_fwd<<<B, 1024, 0, stream>>>(em, trans, mask, states);
  crf_bwd<<<B, 64, 0, stream>>>(states, transT, mask, out, out_stride);
}

// Round 7
// 768.739 us; speedup vs baseline: 1.5495x; 1.5495x over previous
//
#include <hip/hip_runtime.h>

// CRF Viterbi decode: B=256, T=512, K=256, out (B, 514) as int32 tags.
//
// fwd: one block/batch, 16 waves. Wave w: g=w>>1 owns i-rows [32g,32g+32),
// p=w&1 owns j-half [128p,128p+128); lane l owns j-pair {j0,j0+1},
// j0=128p+2l. Payload: 32 v2f over i from transT (TA=col j0, TB=col j1).
// Per step (ONE barrier):
//   read 16 uniform b64 state pairs from wave-private st_w ->
//   32 asm v_pk_add_f32 + 32 asm v_max3_f32 (1 inst/update floor) ->
//   write v2f partial to part[t&1][g][j0] -> barrier ->
//   fold own slice: 4 b32 part reads (2-way, free) + shfl_xor(1) + fmax,
//   ns = mask ? fold+em : ns (old state kept in per-lane reg) ->
//   even lanes write st_w + global states row.
// part[] double-buffered (WAR across the single barrier).
// bwd: recompute backpointers via exact f32 equality scan (unchanged).
// ws: states[B*T*K] f32 (128 MiB) + transT[K*K] f32 (256 KiB).

#define TK 256
#define TT 512

typedef float v2f __attribute__((ext_vector_type(2)));

__device__ __forceinline__ float max3f(float a, float b, float c) {
  float d;
  asm("v_max3_f32 %0, %1, %2, %3" : "=v"(d) : "v"(a), "v"(b), "v"(c));
  return d;
}

__device__ __forceinline__ v2f pk_add(v2f a, v2f b) {
  v2f d;
  asm("v_pk_add_f32 %0, %1, %2" : "=v"(d) : "v"(a), "v"(b));
  return d;
}

__global__ void transpose_kernel(const float* __restrict__ trans,
                                 float* __restrict__ transT) {
  int j = blockIdx.x;
  int i = threadIdx.x;
  transT[(size_t)j * TK + i] = trans[(size_t)i * TK + j];
}

#define K16(X) X(0) X(1) X(2) X(3) X(4) X(5) X(6) X(7) \
               X(8) X(9) X(10) X(11) X(12) X(13) X(14) X(15)

__global__ __launch_bounds__(1024)
__attribute__((amdgpu_waves_per_eu(4, 4)))
void crf_fwd(const float* __restrict__ em,
             const float* __restrict__ transT,
             const int* __restrict__ mask,
             float* __restrict__ states) {
  const int b = blockIdx.x;
  const int tid = threadIdx.x;
  const int lane = tid & 63;
  const int w = tid >> 6;    // wave 0..15
  const int g = w >> 1;      // i-rows [32g, 32g+32)
  const int p = w & 1;       // j-half
  const int j0 = 128 * p + 2 * lane;   // compute-phase cols {j0, j0+1}
  const int jm = 32 * g + (lane >> 1); // fold-phase own j (lane pairs share)

  __shared__ __align__(16) float st_w[16][32];      // wave-private state
  __shared__ __align__(16) float part[2][8][TK];    // double-buffered partials
  __shared__ int mk[TT];

  // payload: TA_k = {trans[32g+2k][j0], trans[32g+2k+1][j0]}, TB_k same for j1
  const float* ta = transT + (size_t)j0 * TK + 32 * g;
  const float* tb = ta + TK;
#define TRD(n) \
  const v2f TA##n = *reinterpret_cast<const v2f*>(ta + 2 * (n)); \
  const v2f TB##n = *reinterpret_cast<const v2f*>(tb + 2 * (n));
  K16(TRD)
#undef TRD

  if (tid < TT) mk[tid] = mask[(size_t)b * TT + tid];

  const size_t base = (size_t)b * TT * TK;
  // init: state0 = emissions[:,0,:]
  float ns = em[base + jm];
  if ((lane & 1) == 0) {
    st_w[w][lane >> 1] = ns;
    if (p == 0) states[base + jm] = ns;
  }
  // em prefetch pipeline (2 deep)
  float em_n1 = em[base + TK + jm];
  float em_n2 = em[base + 2 * TK + jm];
  __syncthreads();  // mk visible; st_w is same-wave only

  const float* stw = st_w[w];

  for (int t = 1; t < TT; ++t) {
    const float em_cur = em_n1;
    em_n1 = em_n2;
    if (t + 2 < TT) em_n2 = em[base + (size_t)(t + 2) * TK + jm];

    // state pairs: SP_k = {s_{32g+2k}, s_{32g+2k+1}} (uniform b64 broadcast)
    // scores: pk_add; fold into two max3 chains (accx for j0, accy for j1)
    v2f a0, b0;
    {
      const v2f SP = *reinterpret_cast<const v2f*>(stw);
      a0 = pk_add(TA0, SP);
      b0 = pk_add(TB0, SP);
    }
    float accx = fmaxf(a0.x, a0.y);
    float accy = fmaxf(b0.x, b0.y);
#define ROWK(n)                                                   \
    if ((n) > 0) {                                                \
      const v2f SP = *reinterpret_cast<const v2f*>(stw + 2 * (n));\
      const v2f aa = pk_add(TA##n, SP);                           \
      const v2f bb = pk_add(TB##n, SP);                           \
      accx = max3f(accx, aa.x, aa.y);                             \
      accy = max3f(accy, bb.x, bb.y);                             \
    }
    K16(ROWK)
#undef ROWK

    *reinterpret_cast<v2f*>(&part[t & 1][g][j0]) = (v2f){accx, accy};
    __syncthreads();

    // fold own slice: lane pair (2m,2m+1) covers j=32g+m; each lane folds
    // 4 of the 8 group-partials, shfl_xor(1) merges the halves.
    const float* pb = &part[t & 1][4 * (lane & 1)][jm];
    const float v0 = pb[0];
    const float v1 = pb[TK];
    const float v2 = pb[2 * TK];
    const float v3 = pb[3 * TK];
    const float f = fmaxf(max3f(v0, v1, v2), v3);
    const float m = fmaxf(f, __shfl_xor(f, 1, 64));
    ns = (mk[t] > 0) ? (m + em_cur) : ns;
    if ((lane & 1) == 0) {
      st_w[w][lane >> 1] = ns;
      if (p == 0) states[base + (size_t)t * TK + jm] = ns;
    }
  }
}

__device__ __forceinline__ float wave_max(float m) {
#pragma unroll
  for (int d = 1; d < 64; d <<= 1) m = fmaxf(m, __shfl_xor(m, d, 64));
  return m;
}

// First index i (lane-major: i = 4*lane + k) whose value equals m.
__device__ __forceinline__ int first_eq_idx(float s0, float s1, float s2,
                                            float s3, float m) {
  unsigned long long b0 = __ballot(s0 == m);
  unsigned long long b1 = __ballot(s1 == m);
  unsigned long long b2 = __ballot(s2 == m);
  unsigned long long b3 = __ballot(s3 == m);
  int best = 0x7fffffff;
  if (b0) best = min(best, 4 * (__ffsll(b0) - 1) + 0);
  if (b1) best = min(best, 4 * (__ffsll(b1) - 1) + 1);
  if (b2) best = min(best, 4 * (__ffsll(b2) - 1) + 2);
  if (b3) best = min(best, 4 * (__ffsll(b3) - 1) + 3);
  return best;
}

// Backward: one wave per batch; 511 serial steps. Recomputes the forward
// argmax exactly (f32 add/max bit-exact; first-occurrence tie-break).
__global__ __launch_bounds__(64, 1) void crf_bwd(const float* __restrict__ states,
                                                 const float* __restrict__ transT,
                                                 const int* __restrict__ mask,
                                                 int* __restrict__ out,
                                                 int out_stride) {
  const int b = blockIdx.x;
  const int lane = threadIdx.x;

  __shared__ int mk[TT];
  for (int q = lane; q < TT; q += 64) mk[q] = mask[(size_t)b * TT + q];
  __syncthreads();

  const size_t sbase = (size_t)b * TT * TK;
  int* outp = out + (size_t)b * out_stride;

  // zero the pad region (harness poisons d_out once)
  for (int q = TT + lane; q < out_stride; q += 64) outp[q] = 0;

  const float* srow = states + sbase;
  float4 r = *reinterpret_cast<const float4*>(srow + (size_t)(TT - 1) * TK + 4 * lane);
  float lm = fmaxf(fmaxf(r.x, r.y), fmaxf(r.z, r.w));
  lm = wave_max(lm);
  int tag = first_eq_idx(r.x, r.y, r.z, r.w, lm);

  auto LOADROW = [&](int rr) -> float4 {
    return *reinterpret_cast<const float4*>(srow + (size_t)rr * TK + 4 * lane);
  };
  float4 p0 = LOADROW(TT - 2), p1 = LOADROW(TT - 3), p2 = LOADROW(TT - 4),
         p3 = LOADROW(TT - 5);

  auto STEP = [&](float4 pr, int t) {
    int mkt = mk[t];
    if (lane == 0) outp[t] = (mkt > 0) ? tag : 0;  // tags * mask
    const float4 tv =
        *reinterpret_cast<const float4*>(transT + (size_t)tag * TK + 4 * lane);
    float s0 = pr.x + tv.x;
    float s1 = pr.y + tv.y;
    float s2 = pr.z + tv.z;
    float s3 = pr.w + tv.w;
    float m = fmaxf(fmaxf(s0, s1), fmaxf(s2, s3));
    m = wave_max(m);
    int prev = first_eq_idx(s0, s1, s2, s3, m);
    tag = (mkt > 0) ? prev : tag;
  };

  int t = TT - 1;
  while (t >= 4) {
    STEP(p0, t);     if (t - 5 >= 0) p0 = LOADROW(t - 5);
    STEP(p1, t - 1); if (t - 6 >= 0) p1 = LOADROW(t - 6);
    STEP(p2, t - 2); if (t - 7 >= 0) p2 = LOADROW(t - 7);
    STEP(p3, t - 3); if (t - 8 >= 0) p3 = LOADROW(t - 8);
    t -= 4;
  }
  STEP(p0, 3);
  STEP(p1, 2);
  STEP(p2, 1);
  if (lane == 0) outp[0] = (mk[0] > 0) ? tag : 0;
}

extern "C" void kernel_launch(void* const* d_in, const int* in_sizes, int n_in,
                              void* d_out, int out_size, void* d_ws, size_t ws_size,
                              hipStream_t stream) {
  const float* em = (const float*)d_in[0];
  const float* trans = (const float*)d_in[1];
  const int* mask = (const int*)d_in[2];
  int* out = (int*)d_out;

  const int B = in_sizes[0] / (TT * TK);      // 256
  const int out_stride = out_size / B;        // 514

  float* states = (float*)d_ws;
  float* transT = states + (size_t)B * TT * TK;

  transpose_kernel<<<TK, TK, 0, stream>>>(trans, transT);
  crf_fwd<<<B, 1024, 0, stream>>>(em, transT, mask, states);
  crf_bwd<<<B, 64, 0, stream>>>(states, transT, mask, out, out_stride);
}